// Round 6
// baseline (250.192 us; speedup 1.0000x reference)
//
#include <hip/hip_runtime.h>
#include <hip/hip_fp16.h>
#include <math.h>

// Problem constants (from reference setup_inputs)
constexpr int N    = 50000;   // nodes
constexpr int E    = 800000;  // edges
constexpr int CIN  = 100;     // input channels
constexpr int CH   = 128;     // hidden channels
constexpr int COUT = 47;      // output channels
constexpr int NOUT = 25000;   // original_size (rows emitted)
constexpr int CP   = 48;      // COUT padded (storage stride)
constexpr int NB   = (N + 255) / 256;        // 196 scan blocks
constexpr int TN   = 128;                    // gemm tile nodes
constexpr int NT   = (N + TN - 1) / TN;      // 391 gemm blocks

// MFMA split-bf16 constants
constexpr int AS  = 72;   // A-stage LDS row stride (ushort) = 144 B (8 bank-starts)
constexpr int HS  = 136;  // h LDS row stride (ushort) = 272 B (16B-aligned rows)
constexpr int W1K = 256;  // w1T row length (k): [agg1 0..99|0|x 0..99|0]
constexpr int W2K = 128;  // w2T row length (k)

// pre_kernel block partition
constexpr int HB = (E + 255) / 256;            // 3125 hist blocks
constexpr int CB = (N * CIN / 4 + 255) / 256;  // 4883 convert blocks
constexpr int PB = 193;                        // prep blocks (49280 elems)

typedef float f32x4 __attribute__((ext_vector_type(4)));
typedef short v8s  __attribute__((ext_vector_type(8)));   // 8 bf16 (4 VGPRs)

// split fp32 -> truncated bf16 hi + bf16(residual) lo.  hi+lo captures ~16
// mantissa bits; 3-term MFMA (hh+hl+lh) leaves ~2^-16 rel error per product.
__device__ __forceinline__ void bsplit(float f, ushort& h, ushort& l) {
    uint u = __float_as_uint(f);
    h = (ushort)(u >> 16);
    float fh = __uint_as_float(u & 0xffff0000u);
    l = (ushort)(__float_as_uint(f - fh) >> 16);
}

// ---------------------------------------------------------------------------
// pre_kernel: fused {hist | convert_x | prep_w} (independent work, one
// launch). hist blocks first (longest latency chain starts earliest); the
// BW-bound convert overlaps hist's atomic latency.
__global__ __launch_bounds__(256) void pre_kernel(
        const int* __restrict__ dst, int* __restrict__ cnt, int* __restrict__ rank,
        const float* __restrict__ x, __half* __restrict__ x16,
        const float* __restrict__ w1l, const float* __restrict__ w1r,
        const float* __restrict__ w2l, const float* __restrict__ w2r,
        const float* __restrict__ b2l,
        ushort* __restrict__ w1T, ushort* __restrict__ w2T,
        float* __restrict__ b2cat) {
    int bid = blockIdx.x, t = threadIdx.x;
    if (bid < HB) {
        // in-degree histogram; rank[i] = slot of edge i within its dst bucket
        int i = bid * 256 + t;
        if (i < E) rank[i] = atomicAdd(&cnt[dst[i]], 1);
    } else if (bid < HB + CB) {
        // x -> fp16 (gather payload 400B -> 200B per row)
        int i = (bid - HB) * 256 + t;
        if (i < N * CIN / 4) {
            float4 v = ((const float4*)x)[i];
            __half2 h0 = __floats2half2_rn(v.x, v.y);
            __half2 h1 = __floats2half2_rn(v.z, v.w);
            union { __half2 h[2]; uint2 u; } U;
            U.h[0] = h0; U.h[1] = h1;
            ((uint2*)x16)[i] = U.u;
        }
    } else {
        // weight transpose + bf16 hi/lo split
        // w1T: [n<128][k<256]: k<100 -> w1l[k][n]; 128<=k<228 -> w1r[k-128][n]
        // w2T: [n<128][k<128]: n<47 -> w2l[k][n]; 64<=n<111 -> w2r[k][n-64]
        int i = (bid - HB - CB) * 256 + t;
        if (i < 128 * W1K) {
            int n = i >> 8, k = i & 255;
            float v = 0.0f;
            if (k < 100)                    v = w1l[(size_t)k * CH + n];
            else if (k >= 128 && k < 228)   v = w1r[(size_t)(k - 128) * CH + n];
            ushort h, l; bsplit(v, h, l);
            w1T[i] = h; w1T[128 * W1K + i] = l;
        } else if (i < 128 * W1K + 128 * W2K) {
            int j = i - 128 * W1K;
            int n = j >> 7, k = j & 127;
            float v = 0.0f;
            if (n < COUT)                      v = w2l[(size_t)k * COUT + n];
            else if (n >= 64 && n < 64 + COUT) v = w2r[(size_t)k * COUT + (n - 64)];
            ushort h, l; bsplit(v, h, l);
            w2T[j] = h; w2T[128 * W2K + j] = l;
        } else {
            int j = i - (128 * W1K + 128 * W2K);
            if (j < 128) b2cat[j] = (j >= 64 && j < 64 + COUT) ? b2l[j - 64] : 0.0f;
        }
    }
}

// CSR stage 2a: per-block exclusive scan of cnt
__global__ __launch_bounds__(256) void scan_blocks(const int* __restrict__ cnt,
        int* __restrict__ row_ptr, int* __restrict__ blkSum) {
    __shared__ int s[256];
    int t = threadIdx.x;
    int i = blockIdx.x * 256 + t;
    int v = (i < N) ? cnt[i] : 0;
    s[t] = v;
    __syncthreads();
    for (int off = 1; off < 256; off <<= 1) {
        int a = s[t];
        int u = (t >= off) ? s[t - off] : 0;
        __syncthreads();
        s[t] = a + u;
        __syncthreads();
    }
    if (i < N) row_ptr[i] = s[t] - v;
    if (t == 255) blkSum[blockIdx.x] = s[255];
}

// CSR stage 2b: each block reduces blkSum[0..bid) itself, applies offset.
__global__ __launch_bounds__(256) void scan_apply(int* __restrict__ row_ptr,
        const int* __restrict__ blkSum) {
    __shared__ int s[256];
    int t = threadIdx.x, bid = blockIdx.x;
    int a = 0;
    for (int j = t; j < bid; j += 256) a += blkSum[j];
    s[t] = a;
    __syncthreads();
    for (int off = 128; off > 0; off >>= 1) {
        if (t < off) s[t] += s[t + off];
        __syncthreads();
    }
    int offset = s[0];
    int i = bid * 256 + t;
    if (i < N) {
        row_ptr[i] += offset;
        if (i == N - 1) row_ptr[N] = E;
    }
}

// CSR stage 3: atomic-free bucket-fill using precomputed rank. nontemporal
// store: col lines are dirtied from all 8 XCDs; nt avoids per-XCD L2 thrash.
__global__ void fill_kernel(const int* __restrict__ src, const int* __restrict__ dst,
        const int* __restrict__ rank, const int* __restrict__ row_ptr,
        int* __restrict__ col) {
    int i = blockIdx.x * blockDim.x + threadIdx.x;
    if (i < E) __builtin_nontemporal_store(src[i], &col[row_ptr[dst[i]] + rank[i]]);
}

// ---------------------------------------------------------------------------
// gather1: fp16 source rows (200B = 25 lanes x 8B). One node per wave
// (uniform trip count); two 32-lane halves take even/odd edges, unroll-4 per
// half; fp32 accumulation; cross-half combine via __shfl_xor(..,32).
// agg1 output nontemporal (via ext-vector f32x4 — HIP float4* is rejected
// by the builtin): write-once data, keeps L2 free for x16.
__global__ __launch_bounds__(256) void gather1_kernel(const __half* __restrict__ x16,
        const int* __restrict__ row_ptr, const int* __restrict__ col,
        float* __restrict__ agg1) {
    int t = threadIdx.x;
    int n = blockIdx.x * 4 + (t >> 6);     // node per wave
    int l = t & 63, half = l >> 5, li = l & 31;
    int b = row_ptr[n], e = row_ptr[n + 1];
    float inv = 1.0f / (float)max(e - b, 1);
    const uint2* xb = (const uint2*)x16;   // row = 25 uint2 (4 halves each)
    bool act = li < 25;
    float4 s0 = make_float4(0.f, 0.f, 0.f, 0.f);
    float4 s1 = make_float4(0.f, 0.f, 0.f, 0.f);
    float4 s2 = make_float4(0.f, 0.f, 0.f, 0.f);
    float4 s3 = make_float4(0.f, 0.f, 0.f, 0.f);
    union { uint2 u; __half2 h[2]; } U0, U1, U2, U3;
    int j = b + half;                      // this half's edge stream (stride 2)
    for (; j + 6 < e; j += 8) {            // 4 edges per half per iteration
        int c0 = col[j], c1 = col[j + 2], c2 = col[j + 4], c3 = col[j + 6];
        if (act) {
            U0.u = xb[(size_t)c0 * 25 + li];
            U1.u = xb[(size_t)c1 * 25 + li];
            U2.u = xb[(size_t)c2 * 25 + li];
            U3.u = xb[(size_t)c3 * 25 + li];
            float2 f0a = __half22float2(U0.h[0]), f0b = __half22float2(U0.h[1]);
            float2 f1a = __half22float2(U1.h[0]), f1b = __half22float2(U1.h[1]);
            float2 f2a = __half22float2(U2.h[0]), f2b = __half22float2(U2.h[1]);
            float2 f3a = __half22float2(U3.h[0]), f3b = __half22float2(U3.h[1]);
            s0.x += f0a.x; s0.y += f0a.y; s0.z += f0b.x; s0.w += f0b.y;
            s1.x += f1a.x; s1.y += f1a.y; s1.z += f1b.x; s1.w += f1b.y;
            s2.x += f2a.x; s2.y += f2a.y; s2.z += f2b.x; s2.w += f2b.y;
            s3.x += f3a.x; s3.y += f3a.y; s3.z += f3b.x; s3.w += f3b.y;
        }
    }
    for (; j < e; j += 2) {                // tail (per-half)
        int c0 = col[j];
        if (act) {
            U0.u = xb[(size_t)c0 * 25 + li];
            float2 f0a = __half22float2(U0.h[0]), f0b = __half22float2(U0.h[1]);
            s0.x += f0a.x; s0.y += f0a.y; s0.z += f0b.x; s0.w += f0b.y;
        }
    }
    float4 s = make_float4(s0.x + s1.x + s2.x + s3.x,
                           s0.y + s1.y + s2.y + s3.y,
                           s0.z + s1.z + s2.z + s3.z,
                           s0.w + s1.w + s2.w + s3.w);
    // cross-half reduce (all 64 lanes alive here)
    s.x += __shfl_xor(s.x, 32, 64);
    s.y += __shfl_xor(s.y, 32, 64);
    s.z += __shfl_xor(s.z, 32, 64);
    s.w += __shfl_xor(s.w, 32, 64);
    if (half == 0 && act) {
        f32x4 r = {s.x * inv, s.y * inv, s.z * inv, s.w * inv};
        __builtin_nontemporal_store(r, (f32x4*)agg1 + (size_t)n * 25 + li);
    }
}

// ---------------------------------------------------------------------------
// fused gemm: split-bf16 MFMA (mfma_f32_16x16x32_bf16, verified layouts:
// A lane: m=l&15, k=(l>>4)*8+j contiguous; C/D: col=l&15, row=(l>>4)*4+reg).
// Stage 1 is ONE GEMM over padded K=256 = [agg1|0|x|0] vs w1T (pretransposed
// hi/lo bf16). A-chunk staging is 1-deep register-prefetched (chunk c+1
// global loads issue before chunk c's LDS write -> HBM latency hides under
// bsplit+barrier+MFMA). h round-trips LDS as hi/lo planes (stride 272B).
// 3-term accumulation hh+hl+lh in fp32. LDS = 69632 B -> 2 blocks/CU.
__global__ __launch_bounds__(256) void fused_gemm(
        const float* __restrict__ agg1, const float* __restrict__ x,
        const ushort* __restrict__ w1T, const float* __restrict__ b1l,
        const ushort* __restrict__ w2T, const float* __restrict__ b2cat,
        __half* __restrict__ gsrc16, float* __restrict__ gself) {
    __shared__ __align__(16) uint lds_u[17408];   // 69632 B
    ushort* Ah = (ushort*)lds_u;                  // [128][AS]  (stage-1 A hi)
    ushort* Al = Ah + 128 * AS;                   // [128][AS]  (stage-1 A lo)
    ushort* Hh = (ushort*)lds_u;                  // [128][HS]  (h hi; aliases Ah/Al)
    ushort* Hl = Hh + 128 * HS;                   // [128][HS]  (h lo)

    int t = threadIdx.x;
    int lane = t & 63;
    int wv = __builtin_amdgcn_readfirstlane(t >> 6);
    int nh = wv & 1, chh = wv >> 1;
    int l15 = lane & 15, lg = lane >> 4;          // frag col/row + k-group
    int base = blockIdx.x * TN;

    const ushort* w1Th = w1T;
    const ushort* w1Tl = w1T + 128 * W1K;
    const ushort* w2Th = w2T;
    const ushort* w2Tl = w2T + 128 * W2K;

    f32x4 acc[4][4];
    #pragma unroll
    for (int nt = 0; nt < 4; ++nt) {
        float bv = b1l[chh * 64 + nt * 16 + l15];
        #pragma unroll
        for (int mt = 0; mt < 4; ++mt)
            acc[mt][nt] = f32x4{bv, bv, bv, bv};
    }

    int srow = t >> 1, sq = t & 1;                // staging: 2 threads/row
    int nmax = N - 1 - base; if (nmax > TN - 1) nmax = TN - 1;
    int srr = srow <= nmax ? srow : nmax;         // clamp tail rows (stores guarded)

    // prologue: chunk 0 (agg1, cols 0..15 f4) into registers
    float4 rv[8];
    {
        const float4* Fp = (const float4*)(agg1 + (size_t)(base + srr) * CIN);
        int cj0 = sq * 8;
        #pragma unroll
        for (int q = 0; q < 8; ++q) {
            int cj = cj0 + q;
            rv[q] = (cj < 25) ? Fp[cj] : make_float4(0.f, 0.f, 0.f, 0.f);
        }
    }

    // ---- stage 1: 4 chunks of 64 k, 1-deep register prefetch
    for (int c = 0; c < 4; ++c) {
        float4 nv[8];
        if (c < 3) {                              // issue next chunk's loads early
            const float* F = (c + 1 < 2) ? agg1 : x;
            const float4* Fp = (const float4*)(F + (size_t)(base + srr) * CIN);
            int cj0 = ((c + 1) & 1) * 16 + sq * 8;
            #pragma unroll
            for (int q = 0; q < 8; ++q) {
                int cj = cj0 + q;
                nv[q] = (cj < 25) ? Fp[cj] : make_float4(0.f, 0.f, 0.f, 0.f);
            }
        }
        #pragma unroll
        for (int q = 0; q < 8; ++q) {             // bsplit + LDS write of rv
            ushort h0, h1, h2, h3, l0, l1, l2, l3;
            bsplit(rv[q].x, h0, l0); bsplit(rv[q].y, h1, l1);
            bsplit(rv[q].z, h2, l2); bsplit(rv[q].w, h3, l3);
            int di = srow * AS + sq * 32 + q * 4;
            *(uint2*)(Ah + di) = make_uint2((uint)h0 | ((uint)h1 << 16),
                                            (uint)h2 | ((uint)h3 << 16));
            *(uint2*)(Al + di) = make_uint2((uint)l0 | ((uint)l1 << 16),
                                            (uint)l2 | ((uint)l3 << 16));
        }
        __syncthreads();
        #pragma unroll
        for (int ks = 0; ks < 2; ++ks) {          // 2 k-steps of 32 per chunk
            v8s ahf[4], alf[4];
            #pragma unroll
            for (int mt = 0; mt < 4; ++mt) {
                int row = nh * 64 + mt * 16 + l15;
                int ko = ks * 32 + lg * 8;
                ahf[mt] = *(const v8s*)(Ah + row * AS + ko);
                alf[mt] = *(const v8s*)(Al + row * AS + ko);
            }
            int kg = c * 64 + ks * 32 + lg * 8;
            #pragma unroll
            for (int nt = 0; nt < 4; ++nt) {
                int n = chh * 64 + nt * 16 + l15;
                v8s bhf = *(const v8s*)(w1Th + (size_t)n * W1K + kg);
                v8s blf = *(const v8s*)(w1Tl + (size_t)n * W1K + kg);
                #pragma unroll
                for (int mt = 0; mt < 4; ++mt) {
                    acc[mt][nt] = __builtin_amdgcn_mfma_f32_16x16x32_bf16(
                        ahf[mt], bhf, acc[mt][nt], 0, 0, 0);
                    acc[mt][nt] = __builtin_amdgcn_mfma_f32_16x16x32_bf16(
                        alf[mt], bhf, acc[mt][nt], 0, 0, 0);
                    acc[mt][nt] = __builtin_amdgcn_mfma_f32_16x16x32_bf16(
                        ahf[mt], blf, acc[mt][nt], 0, 0, 0);
                }
            }
        }
        __syncthreads();
        if (c < 3) {
            #pragma unroll
            for (int q = 0; q < 8; ++q) rv[q] = nv[q];
        }
    }

    // ---- spill h tile to LDS as bf16 hi/lo planes (aliases stage-1 bufs)
    #pragma unroll
    for (int mt = 0; mt < 4; ++mt) {
        #pragma unroll
        for (int nt = 0; nt < 4; ++nt) {
            int ch = chh * 64 + nt * 16 + l15;
            #pragma unroll
            for (int r = 0; r < 4; ++r) {
                int node = nh * 64 + mt * 16 + lg * 4 + r;
                ushort h, l; bsplit(acc[mt][nt][r], h, l);
                Hh[node * HS + ch] = h;
                Hl[node * HS + ch] = l;
            }
        }
    }
    __syncthreads();

    // ---- stage 2: [gsrc|gself] = h @ w2T^T (+ b2cat); no barriers below.
    bool skip = (chh == 1) && (base >= NOUT);
    if (!skip) {
        #pragma unroll
        for (int nt = 0; nt < 4; ++nt) {
            float bv = b2cat[chh * 64 + nt * 16 + l15];
            #pragma unroll
            for (int mt = 0; mt < 4; ++mt)
                acc[mt][nt] = f32x4{bv, bv, bv, bv};
        }
        #pragma unroll
        for (int ks = 0; ks < 4; ++ks) {          // K=128, 4 k-steps of 32
            v8s ahf[4], alf[4];
            #pragma unroll
            for (int mt = 0; mt < 4; ++mt) {
                int node = nh * 64 + mt * 16 + l15;
                int ko = ks * 32 + lg * 8;
                ahf[mt] = *(const v8s*)(Hh + node * HS + ko);
                alf[mt] = *(const v8s*)(Hl + node * HS + ko);
            }
            int kg = ks * 32 + lg * 8;
            #pragma unroll
            for (int nt = 0; nt < 4; ++nt) {
                int n = chh * 64 + nt * 16 + l15;
                v8s bhf = *(const v8s*)(w2Th + (size_t)n * W2K + kg);
                v8s blf = *(const v8s*)(w2Tl + (size_t)n * W2K + kg);
                #pragma unroll
                for (int mt = 0; mt < 4; ++mt) {
                    acc[mt][nt] = __builtin_amdgcn_mfma_f32_16x16x32_bf16(
                        ahf[mt], bhf, acc[mt][nt], 0, 0, 0);
                    acc[mt][nt] = __builtin_amdgcn_mfma_f32_16x16x32_bf16(
                        alf[mt], bhf, acc[mt][nt], 0, 0, 0);
                    acc[mt][nt] = __builtin_amdgcn_mfma_f32_16x16x32_bf16(
                        ahf[mt], blf, acc[mt][nt], 0, 0, 0);
                }
            }
        }
        // store real 48 channels; lanes' l15 covers cols nt*16..nt*16+15.
        // chh==0 wave -> gsrc16 (fp16, cached: final gathers it); chh==1 wave
        // -> gself (f32, nontemporal: read once, coalesced).
        int lim = chh ? NOUT : N;
        #pragma unroll
        for (int nt = 0; nt < 3; ++nt) {          // cols 0..47 only
            int colc = nt * 16 + l15;
            #pragma unroll
            for (int mt = 0; mt < 4; ++mt) {
                #pragma unroll
                for (int r = 0; r < 4; ++r) {
                    int node = base + nh * 64 + mt * 16 + lg * 4 + r;
                    if (node < lim) {
                        if (chh) __builtin_nontemporal_store(acc[mt][nt][r],
                                     gself + (size_t)node * CP + colc);
                        else gsrc16[(size_t)node * CP + colc] =
                                 __float2half(acc[mt][nt][r]);
                    }
                }
            }
        }
    }
}

// ---------------------------------------------------------------------------
// final: 4 nodes per 256-block (one per wave, wave-uniform loop), unroll-4
// fp16 gsrc gather (96B/row). out = log_softmax(mean gsrc + gself).
__global__ __launch_bounds__(256) void final_kernel(const __half* __restrict__ gsrc16,
        const float* __restrict__ gself, const int* __restrict__ row_ptr,
        const int* __restrict__ col, float* __restrict__ out) {
    int t = threadIdx.x;
    int n = blockIdx.x * 4 + (t >> 6);
    int c = t & 63;
    int b = row_ptr[n], e = row_ptr[n + 1];
    float inv = 1.0f / (float)max(e - b, 1);
    float a0 = 0.f, a1 = 0.f, a2 = 0.f, a3 = 0.f;
    if (c < CP) {
        int j = b;
        for (; j + 3 < e; j += 4) {
            a0 += __half2float(gsrc16[(size_t)col[j]     * CP + c]);
            a1 += __half2float(gsrc16[(size_t)col[j + 1] * CP + c]);
            a2 += __half2float(gsrc16[(size_t)col[j + 2] * CP + c]);
            a3 += __half2float(gsrc16[(size_t)col[j + 3] * CP + c]);
        }
        for (; j < e; ++j) a0 += __half2float(gsrc16[(size_t)col[j] * CP + c]);
    }
    float val = (c < COUT)
        ? (((a0 + a1) + (a2 + a3)) * inv + gself[(size_t)n * CP + c]) : -INFINITY;
    float m = val;
    #pragma unroll
    for (int off = 32; off > 0; off >>= 1) m = fmaxf(m, __shfl_xor(m, off, 64));
    float ex = (c < COUT) ? expf(val - m) : 0.f;
    float ssum = ex;
    #pragma unroll
    for (int off = 32; off > 0; off >>= 1) ssum += __shfl_xor(ssum, off, 64);
    if (c < COUT)
        __builtin_nontemporal_store(val - m - logf(ssum),
                                    out + (size_t)n * COUT + c);
}

// ---------------------------------------------------------------------------
extern "C" void kernel_launch(void* const* d_in, const int* in_sizes, int n_in,
                              void* d_out, int out_size, void* d_ws, size_t ws_size,
                              hipStream_t stream) {
    const float* x   = (const float*)d_in[0];
    const int*   ei  = (const int*)d_in[1];   // [2, E]: row 0 = src, row 1 = dst
    const int*   src = ei;
    const int*   dst = ei + E;
    const float* w1l = (const float*)d_in[3];
    const float* b1l = (const float*)d_in[4];
    const float* w1r = (const float*)d_in[5];
    const float* w2l = (const float*)d_in[6];
    const float* b2l = (const float*)d_in[7];
    const float* w2r = (const float*)d_in[8];
    float* out = (float*)d_out;

    // ws: ints [cnt N | row_ptr N+1 | rank E | blkSum NB | col E]
    // floats [agg1 N*CIN | gself NOUT*CP | b2cat 128]
    // halves [gsrc16 N*CP | x16 N*CIN]
    // ushorts [w1T hi+lo 2*128*256 | w2T hi+lo 2*128*128]
    int* cnt     = (int*)d_ws;
    int* row_ptr = cnt + N;
    int* rank    = row_ptr + N + 1;
    int* blkSum  = rank + E;
    int* col     = blkSum + NB;
    size_t intWords = (size_t)N + (N + 1) + E + NB + E;
    intWords = (intWords + 3) & ~(size_t)3;
    float* agg1   = (float*)d_ws + intWords;
    float* gself  = agg1 + (size_t)N * CIN;
    float* b2cat  = gself + (size_t)NOUT * CP;
    __half* gsrc16 = (__half*)(b2cat + 128);
    __half* x16    = gsrc16 + (size_t)N * CP;     // 8B-aligned (counts even)
    ushort* w1T   = (ushort*)(x16 + (size_t)N * CIN);  // 16B-aligned
    ushort* w2T   = w1T + 2 * 128 * W1K;
    // total ws ~46.7 MB (< 58.6 MB proven available)

    (void)hipMemsetAsync(cnt, 0, (size_t)N * sizeof(int), stream);
    pre_kernel  <<<HB + CB + PB, 256, 0, stream>>>(dst, cnt, rank, x, x16,
                                                   w1l, w1r, w2l, w2r, b2l,
                                                   w1T, w2T, b2cat);
    scan_blocks <<<NB, 256, 0, stream>>>(cnt, row_ptr, blkSum);
    scan_apply  <<<NB, 256, 0, stream>>>(row_ptr, blkSum);
    fill_kernel <<<(E + 255) / 256, 256, 0, stream>>>(src, dst, rank, row_ptr, col);
    gather1_kernel<<<N / 4, 256, 0, stream>>>(x16, row_ptr, col, agg1);
    fused_gemm  <<<NT, 256, 0, stream>>>(agg1, x, w1T, b1l, w2T, b2cat, gsrc16, gself);
    final_kernel<<<NOUT / 4, 256, 0, stream>>>(gsrc16, gself, row_ptr, col, out);
}

// Round 7
// 231.130 us; speedup vs baseline: 1.0825x; 1.0825x over previous
//
#include <hip/hip_runtime.h>
#include <hip/hip_fp16.h>
#include <math.h>

// Problem constants (from reference setup_inputs)
constexpr int N    = 50000;   // nodes
constexpr int E    = 800000;  // edges
constexpr int CIN  = 100;     // input channels
constexpr int CH   = 128;     // hidden channels
constexpr int COUT = 47;      // output channels
constexpr int NOUT = 25000;   // original_size (rows emitted)
constexpr int CP   = 48;      // COUT padded (storage stride)
constexpr int NB   = (N + 255) / 256;        // 196 scan blocks
constexpr int TN   = 128;                    // gemm tile nodes
constexpr int NT   = (N + TN - 1) / TN;      // 391 gemm blocks

// MFMA split-bf16 constants
constexpr int AS  = 72;   // A-stage LDS row stride (ushort) = 144 B (8 bank-starts)
constexpr int HS  = 136;  // h LDS row stride (ushort) = 272 B (16B-aligned rows)
constexpr int W1K = 256;  // w1T row length (k): [agg1 0..99|0|x 0..99|0]
constexpr int W2K = 128;  // w2T row length (k)

// pre_kernel block partition
constexpr int HB = (E + 255) / 256;            // 3125 hist blocks
constexpr int CB = (N * CIN / 4 + 255) / 256;  // 4883 convert blocks
constexpr int PB = 193;                        // prep blocks (49280 elems)

typedef float f32x4 __attribute__((ext_vector_type(4)));
typedef short v8s  __attribute__((ext_vector_type(8)));   // 8 bf16 (4 VGPRs)

// split fp32 -> truncated bf16 hi + bf16(residual) lo.  hi+lo captures ~16
// mantissa bits; 3-term MFMA (hh+hl+lh) leaves ~2^-16 rel error per product.
__device__ __forceinline__ void bsplit(float f, ushort& h, ushort& l) {
    uint u = __float_as_uint(f);
    h = (ushort)(u >> 16);
    float fh = __uint_as_float(u & 0xffff0000u);
    l = (ushort)(__float_as_uint(f - fh) >> 16);
}

// ---------------------------------------------------------------------------
// pre_kernel: fused {hist | convert_x | prep_w} (independent work, one
// launch). hist blocks first (longest latency chain starts earliest); the
// BW-bound convert overlaps hist's atomic latency.
__global__ __launch_bounds__(256) void pre_kernel(
        const int* __restrict__ dst, int* __restrict__ cnt, int* __restrict__ rank,
        const float* __restrict__ x, __half* __restrict__ x16,
        const float* __restrict__ w1l, const float* __restrict__ w1r,
        const float* __restrict__ w2l, const float* __restrict__ w2r,
        const float* __restrict__ b2l,
        ushort* __restrict__ w1T, ushort* __restrict__ w2T,
        float* __restrict__ b2cat) {
    int bid = blockIdx.x, t = threadIdx.x;
    if (bid < HB) {
        // in-degree histogram; rank[i] = slot of edge i within its dst bucket
        int i = bid * 256 + t;
        if (i < E) rank[i] = atomicAdd(&cnt[dst[i]], 1);
    } else if (bid < HB + CB) {
        // x -> fp16 (gather payload 400B -> 200B per row)
        int i = (bid - HB) * 256 + t;
        if (i < N * CIN / 4) {
            float4 v = ((const float4*)x)[i];
            __half2 h0 = __floats2half2_rn(v.x, v.y);
            __half2 h1 = __floats2half2_rn(v.z, v.w);
            union { __half2 h[2]; uint2 u; } U;
            U.h[0] = h0; U.h[1] = h1;
            ((uint2*)x16)[i] = U.u;
        }
    } else {
        // weight transpose + bf16 hi/lo split
        // w1T: [n<128][k<256]: k<100 -> w1l[k][n]; 128<=k<228 -> w1r[k-128][n]
        // w2T: [n<128][k<128]: n<47 -> w2l[k][n]; 64<=n<111 -> w2r[k][n-64]
        int i = (bid - HB - CB) * 256 + t;
        if (i < 128 * W1K) {
            int n = i >> 8, k = i & 255;
            float v = 0.0f;
            if (k < 100)                    v = w1l[(size_t)k * CH + n];
            else if (k >= 128 && k < 228)   v = w1r[(size_t)(k - 128) * CH + n];
            ushort h, l; bsplit(v, h, l);
            w1T[i] = h; w1T[128 * W1K + i] = l;
        } else if (i < 128 * W1K + 128 * W2K) {
            int j = i - 128 * W1K;
            int n = j >> 7, k = j & 127;
            float v = 0.0f;
            if (n < COUT)                      v = w2l[(size_t)k * COUT + n];
            else if (n >= 64 && n < 64 + COUT) v = w2r[(size_t)k * COUT + (n - 64)];
            ushort h, l; bsplit(v, h, l);
            w2T[j] = h; w2T[128 * W2K + j] = l;
        } else {
            int j = i - (128 * W1K + 128 * W2K);
            if (j < 128) b2cat[j] = (j >= 64 && j < 64 + COUT) ? b2l[j - 64] : 0.0f;
        }
    }
}

// CSR stage 2a: per-block exclusive scan of cnt
__global__ __launch_bounds__(256) void scan_blocks(const int* __restrict__ cnt,
        int* __restrict__ row_ptr, int* __restrict__ blkSum) {
    __shared__ int s[256];
    int t = threadIdx.x;
    int i = blockIdx.x * 256 + t;
    int v = (i < N) ? cnt[i] : 0;
    s[t] = v;
    __syncthreads();
    for (int off = 1; off < 256; off <<= 1) {
        int a = s[t];
        int u = (t >= off) ? s[t - off] : 0;
        __syncthreads();
        s[t] = a + u;
        __syncthreads();
    }
    if (i < N) row_ptr[i] = s[t] - v;
    if (t == 255) blkSum[blockIdx.x] = s[255];
}

// CSR stage 2b: each block reduces blkSum[0..bid) itself, applies offset.
__global__ __launch_bounds__(256) void scan_apply(int* __restrict__ row_ptr,
        const int* __restrict__ blkSum) {
    __shared__ int s[256];
    int t = threadIdx.x, bid = blockIdx.x;
    int a = 0;
    for (int j = t; j < bid; j += 256) a += blkSum[j];
    s[t] = a;
    __syncthreads();
    for (int off = 128; off > 0; off >>= 1) {
        if (t < off) s[t] += s[t + off];
        __syncthreads();
    }
    int offset = s[0];
    int i = bid * 256 + t;
    if (i < N) {
        row_ptr[i] += offset;
        if (i == N - 1) row_ptr[N] = E;
    }
}

// CSR stage 3: atomic-free bucket-fill using precomputed rank.
// NOTE (R16 post-mortem): col is read by gather1/final immediately after —
// nontemporal store here costs ~18us e2e (L2 no-allocate pushes the gather
// address chain to HBM latency). Plain store.
__global__ void fill_kernel(const int* __restrict__ src, const int* __restrict__ dst,
        const int* __restrict__ rank, const int* __restrict__ row_ptr,
        int* __restrict__ col) {
    int i = blockIdx.x * blockDim.x + threadIdx.x;
    if (i < E) col[row_ptr[dst[i]] + rank[i]] = src[i];
}

// ---------------------------------------------------------------------------
// gather1: fp16 source rows (200B = 25 lanes x 8B). One node per wave
// (uniform trip count); two 32-lane halves take even/odd edges, unroll-4 per
// half; fp32 accumulation; cross-half combine via __shfl_xor(..,32).
// agg1 stored plain (fused_gemm reads it next — keep it cached).
__global__ __launch_bounds__(256) void gather1_kernel(const __half* __restrict__ x16,
        const int* __restrict__ row_ptr, const int* __restrict__ col,
        float* __restrict__ agg1) {
    int t = threadIdx.x;
    int n = blockIdx.x * 4 + (t >> 6);     // node per wave
    int l = t & 63, half = l >> 5, li = l & 31;
    int b = row_ptr[n], e = row_ptr[n + 1];
    float inv = 1.0f / (float)max(e - b, 1);
    const uint2* xb = (const uint2*)x16;   // row = 25 uint2 (4 halves each)
    bool act = li < 25;
    float4 s0 = make_float4(0.f, 0.f, 0.f, 0.f);
    float4 s1 = make_float4(0.f, 0.f, 0.f, 0.f);
    float4 s2 = make_float4(0.f, 0.f, 0.f, 0.f);
    float4 s3 = make_float4(0.f, 0.f, 0.f, 0.f);
    union { uint2 u; __half2 h[2]; } U0, U1, U2, U3;
    int j = b + half;                      // this half's edge stream (stride 2)
    for (; j + 6 < e; j += 8) {            // 4 edges per half per iteration
        int c0 = col[j], c1 = col[j + 2], c2 = col[j + 4], c3 = col[j + 6];
        if (act) {
            U0.u = xb[(size_t)c0 * 25 + li];
            U1.u = xb[(size_t)c1 * 25 + li];
            U2.u = xb[(size_t)c2 * 25 + li];
            U3.u = xb[(size_t)c3 * 25 + li];
            float2 f0a = __half22float2(U0.h[0]), f0b = __half22float2(U0.h[1]);
            float2 f1a = __half22float2(U1.h[0]), f1b = __half22float2(U1.h[1]);
            float2 f2a = __half22float2(U2.h[0]), f2b = __half22float2(U2.h[1]);
            float2 f3a = __half22float2(U3.h[0]), f3b = __half22float2(U3.h[1]);
            s0.x += f0a.x; s0.y += f0a.y; s0.z += f0b.x; s0.w += f0b.y;
            s1.x += f1a.x; s1.y += f1a.y; s1.z += f1b.x; s1.w += f1b.y;
            s2.x += f2a.x; s2.y += f2a.y; s2.z += f2b.x; s2.w += f2b.y;
            s3.x += f3a.x; s3.y += f3a.y; s3.z += f3b.x; s3.w += f3b.y;
        }
    }
    for (; j < e; j += 2) {                // tail (per-half)
        int c0 = col[j];
        if (act) {
            U0.u = xb[(size_t)c0 * 25 + li];
            float2 f0a = __half22float2(U0.h[0]), f0b = __half22float2(U0.h[1]);
            s0.x += f0a.x; s0.y += f0a.y; s0.z += f0b.x; s0.w += f0b.y;
        }
    }
    float4 s = make_float4(s0.x + s1.x + s2.x + s3.x,
                           s0.y + s1.y + s2.y + s3.y,
                           s0.z + s1.z + s2.z + s3.z,
                           s0.w + s1.w + s2.w + s3.w);
    // cross-half reduce (all 64 lanes alive here)
    s.x += __shfl_xor(s.x, 32, 64);
    s.y += __shfl_xor(s.y, 32, 64);
    s.z += __shfl_xor(s.z, 32, 64);
    s.w += __shfl_xor(s.w, 32, 64);
    if (half == 0 && act)
        ((float4*)agg1)[(size_t)n * 25 + li] = make_float4(
            s.x * inv, s.y * inv, s.z * inv, s.w * inv);
}

// ---------------------------------------------------------------------------
// fused gemm: split-bf16 MFMA (mfma_f32_16x16x32_bf16, verified layouts:
// A lane: m=l&15, k=(l>>4)*8+j contiguous; C/D: col=l&15, row=(l>>4)*4+reg).
// Stage 1 is ONE GEMM over padded K=256 = [agg1|0|x|0] vs w1T (pretransposed
// hi/lo bf16). A-chunk staging is 1-deep register-prefetched (chunk c+1
// global loads issue before chunk c's LDS write -> HBM latency hides under
// bsplit+barrier+MFMA). h round-trips LDS as hi/lo planes (stride 272B).
// 3-term accumulation hh+hl+lh in fp32. LDS = 69632 B -> 2 blocks/CU.
// gsrc16/gself stored plain (final reads both — keep cached; R16 lesson).
__global__ __launch_bounds__(256) void fused_gemm(
        const float* __restrict__ agg1, const float* __restrict__ x,
        const ushort* __restrict__ w1T, const float* __restrict__ b1l,
        const ushort* __restrict__ w2T, const float* __restrict__ b2cat,
        __half* __restrict__ gsrc16, float* __restrict__ gself) {
    __shared__ __align__(16) uint lds_u[17408];   // 69632 B
    ushort* Ah = (ushort*)lds_u;                  // [128][AS]  (stage-1 A hi)
    ushort* Al = Ah + 128 * AS;                   // [128][AS]  (stage-1 A lo)
    ushort* Hh = (ushort*)lds_u;                  // [128][HS]  (h hi; aliases Ah/Al)
    ushort* Hl = Hh + 128 * HS;                   // [128][HS]  (h lo)

    int t = threadIdx.x;
    int lane = t & 63;
    int wv = __builtin_amdgcn_readfirstlane(t >> 6);
    int nh = wv & 1, chh = wv >> 1;
    int l15 = lane & 15, lg = lane >> 4;          // frag col/row + k-group
    int base = blockIdx.x * TN;

    const ushort* w1Th = w1T;
    const ushort* w1Tl = w1T + 128 * W1K;
    const ushort* w2Th = w2T;
    const ushort* w2Tl = w2T + 128 * W2K;

    f32x4 acc[4][4];
    #pragma unroll
    for (int nt = 0; nt < 4; ++nt) {
        float bv = b1l[chh * 64 + nt * 16 + l15];
        #pragma unroll
        for (int mt = 0; mt < 4; ++mt)
            acc[mt][nt] = f32x4{bv, bv, bv, bv};
    }

    int srow = t >> 1, sq = t & 1;                // staging: 2 threads/row
    int nmax = N - 1 - base; if (nmax > TN - 1) nmax = TN - 1;
    int srr = srow <= nmax ? srow : nmax;         // clamp tail rows (stores guarded)

    // prologue: chunk 0 (agg1, cols 0..15 f4) into registers
    float4 rv[8];
    {
        const float4* Fp = (const float4*)(agg1 + (size_t)(base + srr) * CIN);
        int cj0 = sq * 8;
        #pragma unroll
        for (int q = 0; q < 8; ++q) {
            int cj = cj0 + q;
            rv[q] = (cj < 25) ? Fp[cj] : make_float4(0.f, 0.f, 0.f, 0.f);
        }
    }

    // ---- stage 1: 4 chunks of 64 k, 1-deep register prefetch
    for (int c = 0; c < 4; ++c) {
        float4 nv[8];
        if (c < 3) {                              // issue next chunk's loads early
            const float* F = (c + 1 < 2) ? agg1 : x;
            const float4* Fp = (const float4*)(F + (size_t)(base + srr) * CIN);
            int cj0 = ((c + 1) & 1) * 16 + sq * 8;
            #pragma unroll
            for (int q = 0; q < 8; ++q) {
                int cj = cj0 + q;
                nv[q] = (cj < 25) ? Fp[cj] : make_float4(0.f, 0.f, 0.f, 0.f);
            }
        }
        #pragma unroll
        for (int q = 0; q < 8; ++q) {             // bsplit + LDS write of rv
            ushort h0, h1, h2, h3, l0, l1, l2, l3;
            bsplit(rv[q].x, h0, l0); bsplit(rv[q].y, h1, l1);
            bsplit(rv[q].z, h2, l2); bsplit(rv[q].w, h3, l3);
            int di = srow * AS + sq * 32 + q * 4;
            *(uint2*)(Ah + di) = make_uint2((uint)h0 | ((uint)h1 << 16),
                                            (uint)h2 | ((uint)h3 << 16));
            *(uint2*)(Al + di) = make_uint2((uint)l0 | ((uint)l1 << 16),
                                            (uint)l2 | ((uint)l3 << 16));
        }
        __syncthreads();
        #pragma unroll
        for (int ks = 0; ks < 2; ++ks) {          // 2 k-steps of 32 per chunk
            v8s ahf[4], alf[4];
            #pragma unroll
            for (int mt = 0; mt < 4; ++mt) {
                int row = nh * 64 + mt * 16 + l15;
                int ko = ks * 32 + lg * 8;
                ahf[mt] = *(const v8s*)(Ah + row * AS + ko);
                alf[mt] = *(const v8s*)(Al + row * AS + ko);
            }
            int kg = c * 64 + ks * 32 + lg * 8;
            #pragma unroll
            for (int nt = 0; nt < 4; ++nt) {
                int n = chh * 64 + nt * 16 + l15;
                v8s bhf = *(const v8s*)(w1Th + (size_t)n * W1K + kg);
                v8s blf = *(const v8s*)(w1Tl + (size_t)n * W1K + kg);
                #pragma unroll
                for (int mt = 0; mt < 4; ++mt) {
                    acc[mt][nt] = __builtin_amdgcn_mfma_f32_16x16x32_bf16(
                        ahf[mt], bhf, acc[mt][nt], 0, 0, 0);
                    acc[mt][nt] = __builtin_amdgcn_mfma_f32_16x16x32_bf16(
                        alf[mt], bhf, acc[mt][nt], 0, 0, 0);
                    acc[mt][nt] = __builtin_amdgcn_mfma_f32_16x16x32_bf16(
                        ahf[mt], blf, acc[mt][nt], 0, 0, 0);
                }
            }
        }
        __syncthreads();
        if (c < 3) {
            #pragma unroll
            for (int q = 0; q < 8; ++q) rv[q] = nv[q];
        }
    }

    // ---- spill h tile to LDS as bf16 hi/lo planes (aliases stage-1 bufs)
    #pragma unroll
    for (int mt = 0; mt < 4; ++mt) {
        #pragma unroll
        for (int nt = 0; nt < 4; ++nt) {
            int ch = chh * 64 + nt * 16 + l15;
            #pragma unroll
            for (int r = 0; r < 4; ++r) {
                int node = nh * 64 + mt * 16 + lg * 4 + r;
                ushort h, l; bsplit(acc[mt][nt][r], h, l);
                Hh[node * HS + ch] = h;
                Hl[node * HS + ch] = l;
            }
        }
    }
    __syncthreads();

    // ---- stage 2: [gsrc|gself] = h @ w2T^T (+ b2cat); no barriers below.
    bool skip = (chh == 1) && (base >= NOUT);
    if (!skip) {
        #pragma unroll
        for (int nt = 0; nt < 4; ++nt) {
            float bv = b2cat[chh * 64 + nt * 16 + l15];
            #pragma unroll
            for (int mt = 0; mt < 4; ++mt)
                acc[mt][nt] = f32x4{bv, bv, bv, bv};
        }
        #pragma unroll
        for (int ks = 0; ks < 4; ++ks) {          // K=128, 4 k-steps of 32
            v8s ahf[4], alf[4];
            #pragma unroll
            for (int mt = 0; mt < 4; ++mt) {
                int node = nh * 64 + mt * 16 + l15;
                int ko = ks * 32 + lg * 8;
                ahf[mt] = *(const v8s*)(Hh + node * HS + ko);
                alf[mt] = *(const v8s*)(Hl + node * HS + ko);
            }
            int kg = ks * 32 + lg * 8;
            #pragma unroll
            for (int nt = 0; nt < 4; ++nt) {
                int n = chh * 64 + nt * 16 + l15;
                v8s bhf = *(const v8s*)(w2Th + (size_t)n * W2K + kg);
                v8s blf = *(const v8s*)(w2Tl + (size_t)n * W2K + kg);
                #pragma unroll
                for (int mt = 0; mt < 4; ++mt) {
                    acc[mt][nt] = __builtin_amdgcn_mfma_f32_16x16x32_bf16(
                        ahf[mt], bhf, acc[mt][nt], 0, 0, 0);
                    acc[mt][nt] = __builtin_amdgcn_mfma_f32_16x16x32_bf16(
                        alf[mt], bhf, acc[mt][nt], 0, 0, 0);
                    acc[mt][nt] = __builtin_amdgcn_mfma_f32_16x16x32_bf16(
                        ahf[mt], blf, acc[mt][nt], 0, 0, 0);
                }
            }
        }
        // store real 48 channels; lanes' l15 covers cols nt*16..nt*16+15.
        int lim = chh ? NOUT : N;
        #pragma unroll
        for (int nt = 0; nt < 3; ++nt) {          // cols 0..47 only
            int colc = nt * 16 + l15;
            #pragma unroll
            for (int mt = 0; mt < 4; ++mt) {
                #pragma unroll
                for (int r = 0; r < 4; ++r) {
                    int node = base + nh * 64 + mt * 16 + lg * 4 + r;
                    if (node < lim) {
                        if (chh) gself[(size_t)node * CP + colc] = acc[mt][nt][r];
                        else gsrc16[(size_t)node * CP + colc] =
                                 __float2half(acc[mt][nt][r]);
                    }
                }
            }
        }
    }
}

// ---------------------------------------------------------------------------
// final: 4 nodes per 256-block (one per wave, wave-uniform loop), unroll-4
// fp16 gsrc gather (96B/row). out = log_softmax(mean gsrc + gself).
// out nt store is safe: out is never read on-device.
__global__ __launch_bounds__(256) void final_kernel(const __half* __restrict__ gsrc16,
        const float* __restrict__ gself, const int* __restrict__ row_ptr,
        const int* __restrict__ col, float* __restrict__ out) {
    int t = threadIdx.x;
    int n = blockIdx.x * 4 + (t >> 6);
    int c = t & 63;
    int b = row_ptr[n], e = row_ptr[n + 1];
    float inv = 1.0f / (float)max(e - b, 1);
    float a0 = 0.f, a1 = 0.f, a2 = 0.f, a3 = 0.f;
    if (c < CP) {
        int j = b;
        for (; j + 3 < e; j += 4) {
            a0 += __half2float(gsrc16[(size_t)col[j]     * CP + c]);
            a1 += __half2float(gsrc16[(size_t)col[j + 1] * CP + c]);
            a2 += __half2float(gsrc16[(size_t)col[j + 2] * CP + c]);
            a3 += __half2float(gsrc16[(size_t)col[j + 3] * CP + c]);
        }
        for (; j < e; ++j) a0 += __half2float(gsrc16[(size_t)col[j] * CP + c]);
    }
    float val = (c < COUT)
        ? (((a0 + a1) + (a2 + a3)) * inv + gself[(size_t)n * CP + c]) : -INFINITY;
    float m = val;
    #pragma unroll
    for (int off = 32; off > 0; off >>= 1) m = fmaxf(m, __shfl_xor(m, off, 64));
    float ex = (c < COUT) ? expf(val - m) : 0.f;
    float ssum = ex;
    #pragma unroll
    for (int off = 32; off > 0; off >>= 1) ssum += __shfl_xor(ssum, off, 64);
    if (c < COUT)
        __builtin_nontemporal_store(val - m - logf(ssum),
                                    out + (size_t)n * COUT + c);
}

// ---------------------------------------------------------------------------
extern "C" void kernel_launch(void* const* d_in, const int* in_sizes, int n_in,
                              void* d_out, int out_size, void* d_ws, size_t ws_size,
                              hipStream_t stream) {
    const float* x   = (const float*)d_in[0];
    const int*   ei  = (const int*)d_in[1];   // [2, E]: row 0 = src, row 1 = dst
    const int*   src = ei;
    const int*   dst = ei + E;
    const float* w1l = (const float*)d_in[3];
    const float* b1l = (const float*)d_in[4];
    const float* w1r = (const float*)d_in[5];
    const float* w2l = (const float*)d_in[6];
    const float* b2l = (const float*)d_in[7];
    const float* w2r = (const float*)d_in[8];
    float* out = (float*)d_out;

    // ws: ints [cnt N | row_ptr N+1 | rank E | blkSum NB | col E]
    // floats [agg1 N*CIN | gself NOUT*CP | b2cat 128]
    // halves [gsrc16 N*CP | x16 N*CIN]
    // ushorts [w1T hi+lo 2*128*256 | w2T hi+lo 2*128*128]
    int* cnt     = (int*)d_ws;
    int* row_ptr = cnt + N;
    int* rank    = row_ptr + N + 1;
    int* blkSum  = rank + E;
    int* col     = blkSum + NB;
    size_t intWords = (size_t)N + (N + 1) + E + NB + E;
    intWords = (intWords + 3) & ~(size_t)3;
    float* agg1   = (float*)d_ws + intWords;
    float* gself  = agg1 + (size_t)N * CIN;
    float* b2cat  = gself + (size_t)NOUT * CP;
    __half* gsrc16 = (__half*)(b2cat + 128);
    __half* x16    = gsrc16 + (size_t)N * CP;     // 8B-aligned (counts even)
    ushort* w1T   = (ushort*)(x16 + (size_t)N * CIN);  // 16B-aligned
    ushort* w2T   = w1T + 2 * 128 * W1K;
    // total ws ~46.7 MB (< 58.6 MB proven available)

    (void)hipMemsetAsync(cnt, 0, (size_t)N * sizeof(int), stream);
    pre_kernel  <<<HB + CB + PB, 256, 0, stream>>>(dst, cnt, rank, x, x16,
                                                   w1l, w1r, w2l, w2r, b2l,
                                                   w1T, w2T, b2cat);
    scan_blocks <<<NB, 256, 0, stream>>>(cnt, row_ptr, blkSum);
    scan_apply  <<<NB, 256, 0, stream>>>(row_ptr, blkSum);
    fill_kernel <<<(E + 255) / 256, 256, 0, stream>>>(src, dst, rank, row_ptr, col);
    gather1_kernel<<<N / 4, 256, 0, stream>>>(x16, row_ptr, col, agg1);
    fused_gemm  <<<NT, 256, 0, stream>>>(agg1, x, w1T, b1l, w2T, b2cat, gsrc16, gself);
    final_kernel<<<NOUT / 4, 256, 0, stream>>>(gsrc16, gself, row_ptr, col, out);
}